// Round 1
// 685.835 us; speedup vs baseline: 1.0502x; 1.0502x over previous
//
#include <hip/hip_runtime.h>
#include <math.h>

#define T_SEQ 2048
#define BATCH 4
#define E_DIM 2048
#define NHEAD 16
#define HDIM 128
#define RMS_EPS 1.1920929e-07f
#define NQT (T_SEQ / 128)          // 16 q-tiles of 128

typedef unsigned short u16;
typedef __attribute__((ext_vector_type(8))) unsigned short u16x8;
typedef __attribute__((ext_vector_type(8))) short bf16x8;
typedef __attribute__((ext_vector_type(4))) float f32x4;

typedef const __attribute__((address_space(1))) unsigned int g_u32;
typedef __attribute__((address_space(3))) unsigned int l_u32;

static __device__ __forceinline__ u16 f2b(float f) {
  unsigned int u = __builtin_bit_cast(unsigned int, f);
  u += 0x7fffu + ((u >> 16) & 1u);
  return (u16)(u >> 16);
}
static __device__ __forceinline__ float b2f(u16 v) {
  return __builtin_bit_cast(float, ((unsigned int)v) << 16);
}

// ---------------- fp32 -> bf16 convert (x only) ----------------
__global__ __launch_bounds__(256) void convert_f32_bf16(
    const float* __restrict__ src, u16* __restrict__ dst, int n) {
  int i = (blockIdx.x * 256 + threadIdx.x) * 4;
  if (i >= n) return;
  float4 v = *reinterpret_cast<const float4*>(src + i);
  ushort4 o;
  o.x = f2b(v.x); o.y = f2b(v.y); o.z = f2b(v.z); o.w = f2b(v.w);
  *reinterpret_cast<ushort4*>(dst + i) = o;
}

// ---------------- fused fp32->bf16 convert + transpose: Wt[n][k]=W[k][n] ----
__global__ __launch_bounds__(256) void convt_w_k(
    const float* __restrict__ W, u16* __restrict__ Wt) {
  __shared__ u16 tile[64][72];
  int c0 = blockIdx.x * 64;
  int r0 = blockIdx.y * 64;
  int tid = threadIdx.x;
  int lrow = tid >> 2;
  int lcol = (tid & 3) * 16;
#pragma unroll
  for (int i = 0; i < 4; ++i) {
    float4 v = *reinterpret_cast<const float4*>(
        W + (long long)(r0 + lrow) * E_DIM + c0 + lcol + i * 4);
    tile[lrow][lcol + i * 4 + 0] = f2b(v.x);
    tile[lrow][lcol + i * 4 + 1] = f2b(v.y);
    tile[lrow][lcol + i * 4 + 2] = f2b(v.z);
    tile[lrow][lcol + i * 4 + 3] = f2b(v.w);
  }
  __syncthreads();
  int wrow = tid >> 2;
  int wcol = (tid & 3) * 16;
  u16 o[16];
#pragma unroll
  for (int i = 0; i < 16; ++i) o[i] = tile[wcol + i][wrow];
  u16* dst = Wt + (long long)(c0 + wrow) * E_DIM + r0 + wcol;
  *reinterpret_cast<u16x8*>(dst)     = *reinterpret_cast<u16x8*>(&o[0]);
  *reinterpret_cast<u16x8*>(dst + 8) = *reinterpret_cast<u16x8*>(&o[8]);
}

// ---------------- rope tables (double precision trig) ----------------
__global__ __launch_bounds__(256) void rope_tables_k(
    float* __restrict__ cost, float* __restrict__ sint) {
  int idx = blockIdx.x * 256 + threadIdx.x;
  int i = idx & 63, t = idx >> 6;
  double inv = pow(10000.0, -(double)i / 64.0);
  double ang = (double)t * inv;
  cost[idx] = (float)cos(ang);
  sint[idx] = (float)sin(ang);
}

// ---------------- fused rope + rmsnorm (in-place on bf16 Q and K) ----------
__global__ __launch_bounds__(256) void rope_rms_k(
    u16* __restrict__ Qb, u16* __restrict__ Kb, const float* __restrict__ cost,
    const float* __restrict__ sint) {
  int half = gridDim.x >> 1;
  int isK = blockIdx.x >= half;
  u16* qk = isK ? Kb : Qb;
  float outscale = isK ? 1.0f : 0.08838834764831845f;  // fold 1/sqrt(128) into Q
  int wave = threadIdx.x >> 6;
  int lane = threadIdx.x & 63;
  long long row = (long long)(blockIdx.x - (isK ? half : 0)) * 4 + wave;
  int th = (int)(row >> 4);
  int t = th & (T_SEQ - 1);
  u16* p = qk + row * HDIM;
  float x1 = b2f(p[lane]);
  float x2 = b2f(p[lane + 64]);
  float c = cost[t * 64 + lane];
  float s = sint[t * 64 + lane];
  float o1 = x1 * c - x2 * s;
  float o2 = x1 * s + x2 * c;
  float ss = o1 * o1 + o2 * o2;
#pragma unroll
  for (int m = 32; m >= 1; m >>= 1) ss += __shfl_xor(ss, m, 64);
  float r = rsqrtf(ss * (1.0f / 128.0f) + RMS_EPS) * outscale;
  p[lane] = f2b(o1 * r);
  p[lane + 64] = f2b(o2 * r);
}

// ---------------- V transpose: [B,T,H,D] -> per (b,h): [D][T] ----------------
__global__ __launch_bounds__(256) void transpose_v_k(
    const u16* __restrict__ V, u16* __restrict__ Vt) {
  __shared__ u16 tile[64][72];
  int t0 = blockIdx.x * 64, d0 = blockIdx.y * 64;
  int bh = blockIdx.z;
  int b = bh >> 4, h = bh & 15;
  int tid = threadIdx.x;
  int lrow = tid >> 3;
  int lcol = (tid & 7) * 8;
#pragma unroll
  for (int pass = 0; pass < 2; ++pass) {
    int row = lrow + pass * 32;
    const u16* src = V + ((((long long)b * T_SEQ + t0 + row) * NHEAD + h) << 7) + d0 + lcol;
    *reinterpret_cast<u16x8*>(&tile[row][lcol]) = *reinterpret_cast<const u16x8*>(src);
  }
  __syncthreads();
#pragma unroll
  for (int pass = 0; pass < 2; ++pass) {
    int drow = (tid >> 3) + pass * 32;
    int tcol = (tid & 7) * 8;
    u16x8 o;
#pragma unroll
    for (int i = 0; i < 8; ++i) o[i] = tile[tcol + i][drow];
    u16* dst = Vt + ((long long)bh * HDIM + d0 + drow) * T_SEQ + t0 + tcol;
    *reinterpret_cast<u16x8*>(dst) = o;
  }
}

// ---------------- bf16 MFMA GEMM: 256x256 tile, 8-phase schedule ------------
// C[M,N] = A[M,K] * Bt[N,K]^T.  512 threads = 8 waves (2M x 4N), each wave
// owns 128x64 output (8x4 frags of 16x16, mfma_f32_16x16x32_bf16, BK=64).
// LDS: 2 x (A 256x64 + B 256x64) bf16 = 128 KiB, double buffered.
// Staging: global_load_lds width=16, linear LDS dest; bank-conflict swizzle
// chunk^=(row&7) applied on the GLOBAL source and on ds_read (rule #21).
// Counted vmcnt(6) once per K-tile (T4); raw s_barrier; setprio around MFMA.
__global__ __launch_bounds__(512, 2) void gemm_bt_k(
    const u16* __restrict__ A,
    const u16* __restrict__ Bt0, const u16* __restrict__ Bt1, const u16* __restrict__ Bt2,
    u16* __restrict__ C0, u16* __restrict__ C1, u16* __restrict__ C2,
    float* __restrict__ Cf, int M, int N, int K) {
  const u16* Bt = blockIdx.z == 0 ? Bt0 : (blockIdx.z == 1 ? Bt1 : Bt2);
  u16* C = blockIdx.z == 0 ? C0 : (blockIdx.z == 1 ? C1 : C2);
  __shared__ u16 As[2][256 * 64];
  __shared__ u16 Bs[2][256 * 64];
  const int tid = threadIdx.x;
  const int lane = tid & 63, wave = tid >> 6;
  const int wm = wave >> 2, wn = wave & 3;   // 2 x 4 wave grid
  const int m0 = blockIdx.y * 256, n0 = blockIdx.x * 256;
  const int lr = lane & 15, lq = lane >> 4, l7 = lane & 7;
  const int NT = K >> 6;

  // Staging halves (striped so each half is fully read in one phase):
  //   A half h = rows with bit6==h   (read: phase1 -> h0, phase3 -> h1)
  //   B half h = rows with bit5==h   (read: phase1 -> h0, phase2 -> h1)
  // Per half: 2 loads/thread; per-wave LDS dest is linear (8 rows x 128B).
  int rowA[2][2], rowB[2][2];
  const u16* gA[2][2];
  const u16* gB[2][2];
#pragma unroll
  for (int l = 0; l < 2; ++l) {
    int rihb = l * 64 + wave * 8;
#pragma unroll
    for (int h = 0; h < 2; ++h) {
      int ra = ((rihb >> 6) << 7) + h * 64 + (rihb & 63);
      int rb = ((rihb >> 5) << 6) + h * 32 + (rihb & 31);
      rowA[h][l] = ra;
      rowB[h][l] = rb;
      int rA = ra + (lane >> 3);
      int rB = rb + (lane >> 3);
      // inverse-swizzled global source: LDS[r][c] <- G[r][c ^ (r&7)]
      gA[h][l] = A + (long long)(m0 + rA) * K + ((l7 ^ (rA & 7)) * 8);
      gB[h][l] = Bt + (long long)(n0 + rB) * K + ((l7 ^ (rB & 7)) * 8);
    }
  }

  f32x4 acc[8][4] = {};

#define STAGE_A(tile, h)                                                      \
  do {                                                                        \
    if ((tile) < NT) {                                                        \
      int _b = (tile) & 1;                                                    \
      long long _ko = (long long)(tile) << 6;                                 \
      __builtin_amdgcn_global_load_lds((g_u32*)(gA[h][0] + _ko),              \
          (l_u32*)(&As[_b][rowA[h][0] * 64]), 16, 0, 0);                      \
      __builtin_amdgcn_global_load_lds((g_u32*)(gA[h][1] + _ko),              \
          (l_u32*)(&As[_b][rowA[h][1] * 64]), 16, 0, 0);                      \
    }                                                                         \
  } while (0)
#define STAGE_B(tile, h)                                                      \
  do {                                                                        \
    if ((tile) < NT) {                                                        \
      int _b = (tile) & 1;                                                    \
      long long _ko = (long long)(tile) << 6;                                 \
      __builtin_amdgcn_global_load_lds((g_u32*)(gB[h][0] + _ko),              \
          (l_u32*)(&Bs[_b][rowB[h][0] * 64]), 16, 0, 0);                      \
      __builtin_amdgcn_global_load_lds((g_u32*)(gB[h][1] + _ko),              \
          (l_u32*)(&Bs[_b][rowB[h][1] * 64]), 16, 0, 0);                      \
    }                                                                         \
  } while (0)

  // prologue: tile0 fully (B0,B1,A0,A1) + tile1 (B0,B1,A0); keep 3 halves
  // in flight (6 loads) across the first barrier.
  STAGE_B(0, 0); STAGE_B(0, 1); STAGE_A(0, 0); STAGE_A(0, 1);
  STAGE_B(1, 0); STAGE_B(1, 1); STAGE_A(1, 0);
  asm volatile("s_waitcnt vmcnt(6)" ::: "memory");
  __builtin_amdgcn_s_barrier();
  __builtin_amdgcn_sched_barrier(0);

  for (int t = 0; t < NT; ++t) {
    const u16* Ab = As[t & 1];
    const u16* Bb = Bs[t & 1];
    bf16x8 aA[4][2], bB[4][2];

#define LD_A(mt, ks)                                                          \
  (*reinterpret_cast<const bf16x8*>(                                          \
      Ab + (wm * 128 + (mt) * 16 + lr) * 64 + ((((ks) << 2) + lq) ^ l7) * 8))
#define LD_B(nt, ks)                                                          \
  (*reinterpret_cast<const bf16x8*>(                                          \
      Bb + (wn * 64 + (nt) * 16 + lr) * 64 + ((((ks) << 2) + lq) ^ l7) * 8))
#define MFMA_QUAD(mh, nh)                                                     \
  _Pragma("unroll") for (int mi = 0; mi < 4; ++mi)                            \
  _Pragma("unroll") for (int ni = 0; ni < 2; ++ni)                            \
  _Pragma("unroll") for (int ks = 0; ks < 2; ++ks)                            \
    acc[(mh) * 4 + mi][(nh) * 2 + ni] =                                       \
        __builtin_amdgcn_mfma_f32_16x16x32_bf16(aA[mi][ks],                   \
            bB[(nh) * 2 + ni][ks], acc[(mh) * 4 + mi][(nh) * 2 + ni], 0, 0, 0);

    // ---- phase 1: quad(mh=0,nh=0); ds: A-h0(8) + B-nt01(4); stage t+1:A1
#pragma unroll
    for (int mi = 0; mi < 4; ++mi) { aA[mi][0] = LD_A(mi, 0); aA[mi][1] = LD_A(mi, 1); }
#pragma unroll
    for (int ni = 0; ni < 2; ++ni) { bB[ni][0] = LD_B(ni, 0); bB[ni][1] = LD_B(ni, 1); }
    STAGE_A(t + 1, 1);
    __builtin_amdgcn_s_barrier();
    asm volatile("s_waitcnt lgkmcnt(0)" ::: "memory");
    __builtin_amdgcn_sched_barrier(0);
    __builtin_amdgcn_s_setprio(1);
    MFMA_QUAD(0, 0);
    __builtin_amdgcn_s_setprio(0);
    __builtin_amdgcn_s_barrier();

    // ---- phase 2: quad(0,1); ds: B-nt23(4); stage t+2:B0 (last read p1)
#pragma unroll
    for (int ni = 0; ni < 2; ++ni) { bB[2 + ni][0] = LD_B(2 + ni, 0); bB[2 + ni][1] = LD_B(2 + ni, 1); }
    STAGE_B(t + 2, 0);
    __builtin_amdgcn_s_barrier();
    asm volatile("s_waitcnt lgkmcnt(0)" ::: "memory");
    __builtin_amdgcn_sched_barrier(0);
    __builtin_amdgcn_s_setprio(1);
    MFMA_QUAD(0, 1);
    __builtin_amdgcn_s_setprio(0);
    __builtin_amdgcn_s_barrier();

    // ---- phase 3: quad(1,0); ds: A-h1(8); stage t+2:B1 (last read p2)
#pragma unroll
    for (int mi = 0; mi < 4; ++mi) { aA[mi][0] = LD_A(4 + mi, 0); aA[mi][1] = LD_A(4 + mi, 1); }
    STAGE_B(t + 2, 1);
    __builtin_amdgcn_s_barrier();
    asm volatile("s_waitcnt lgkmcnt(0)" ::: "memory");
    __builtin_amdgcn_sched_barrier(0);
    __builtin_amdgcn_s_setprio(1);
    MFMA_QUAD(1, 0);
    __builtin_amdgcn_s_setprio(0);
    __builtin_amdgcn_s_barrier();

    // ---- phase 4: quad(1,1); no ds; stage t+2:A0 (last read p1); vmcnt
    STAGE_A(t + 2, 0);
    __builtin_amdgcn_s_barrier();
    __builtin_amdgcn_s_setprio(1);
    MFMA_QUAD(1, 1);
    __builtin_amdgcn_s_setprio(0);
    if (t < NT - 2) {
      asm volatile("s_waitcnt vmcnt(6)" ::: "memory");   // keep 3 halves in flight
    } else {
      asm volatile("s_waitcnt vmcnt(0)" ::: "memory");   // tail drain
    }
    __builtin_amdgcn_s_barrier();
    __builtin_amdgcn_sched_barrier(0);
  }
#undef LD_A
#undef LD_B
#undef MFMA_QUAD
#undef STAGE_A
#undef STAGE_B

  // epilogue: C col = lane&15, row = (lane>>4)*4 + reg   (16x16 C/D layout)
#pragma unroll
  for (int mt = 0; mt < 8; ++mt)
#pragma unroll
    for (int nt = 0; nt < 4; ++nt) {
      long long col = n0 + wn * 64 + nt * 16 + lr;
#pragma unroll
      for (int r = 0; r < 4; ++r) {
        long long row = m0 + wm * 128 + mt * 16 + lq * 4 + r;
        float v = acc[mt][nt][r];
        if (Cf) Cf[row * N + col] = v;
        else C[row * N + col] = f2b(v);
      }
    }
}

// ---------------- causal flash attention v3 (unchanged) ----------------
__global__ __launch_bounds__(256, 3) void attn_k(
    const u16* __restrict__ Q, const u16* __restrict__ K,
    const u16* __restrict__ Vt, u16* __restrict__ Y) {
  __shared__ u16 Ks[64 * 128];        // row=key, 16 chunks/row, slot=(g+key)&15
  __shared__ u16 Vs[128 * 64];        // row=d, 8 chunks/row, slot=(g+d)&7
  __shared__ u16 Ps[4][32 * 72];      // per-wave P [q][key], pad 64->72
  __shared__ float Al[4][32];         // per-wave alpha / l broadcast
  int pair = blockIdx.x;              // 0..NQT/2-1
  int bh = blockIdx.y;
  int b = bh >> 4, h = bh & 15;
  int tid = threadIdx.x, lane = tid & 63, wave = tid >> 6;
  int lr = lane & 15, lq = lane >> 4;

  const u16* kp[4];
  const u16* vp[4];
#pragma unroll
  for (int p = 0; p < 4; ++p) {
    int c = p * 256 + wave * 64 + lane;
    int key = c >> 4, sk = c & 15, gk = (sk - key) & 15;
    kp[p] = K + (((long long)b * T_SEQ + key) * NHEAD + h) * HDIM + gk * 8;
    int d = c >> 3, sv = c & 7, gv = (sv - d) & 7;
    vp[p] = Vt + ((long long)bh * HDIM + d) * T_SEQ + gv * 8;
  }

#pragma unroll 1
  for (int phase = 0; phase < 2; ++phase) {
    int qt = phase == 0 ? (NQT - 1 - pair) : pair;
    int qbase = qt * 128 + wave * 32;

    bf16x8 aq[2][4];
#pragma unroll
    for (int n2 = 0; n2 < 2; ++n2) {
      const u16* qp = Q + (((long long)b * T_SEQ + qbase + n2 * 16 + lr) * NHEAD + h) * HDIM;
#pragma unroll
      for (int kt = 0; kt < 4; ++kt)
        aq[n2][kt] = *reinterpret_cast<const bf16x8*>(qp + kt * 32 + lq * 8);
    }

    float m_s[2], l_s[2];
#pragma unroll
    for (int n2 = 0; n2 < 2; ++n2) { m_s[n2] = -INFINITY; l_s[n2] = 0.f; }
    f32x4 o[2][8] = {};

    int niter = 2 * qt + 2;
    for (int j = 0; j < niter; ++j) {
      __syncthreads();
#pragma unroll
      for (int p = 0; p < 4; ++p) {
        __builtin_amdgcn_global_load_lds(
            (g_u32*)(kp[p] + (long long)j * 64 * NHEAD * HDIM),
            (l_u32*)(Ks + p * 2048 + wave * 512), 16, 0, 0);
        __builtin_amdgcn_global_load_lds(
            (g_u32*)(vp[p] + j * 64),
            (l_u32*)(Vs + p * 2048 + wave * 512), 16, 0, 0);
      }
      __syncthreads();

      f32x4 s[4][2];
#pragma unroll
      for (int mt = 0; mt < 4; ++mt) {
        int key = mt * 16 + lr;
        bf16x8 ak[4];
#pragma unroll
        for (int kt = 0; kt < 4; ++kt) {
          int slot = (kt * 4 + lq + key) & 15;
          ak[kt] = *reinterpret_cast<const bf16x8*>(&Ks[key * 128 + slot * 8]);
        }
#pragma unroll
        for (int n2 = 0; n2 < 2; ++n2) {
          f32x4 acc = {};
#pragma unroll
          for (int kt = 0; kt < 4; ++kt)
            acc = __builtin_amdgcn_mfma_f32_16x16x32_bf16(ak[kt], aq[n2][kt], acc, 0, 0, 0);
          s[mt][n2] = acc;
        }
      }

      if (j >= 2 * qt) {
#pragma unroll
        for (int mt = 0; mt < 4; ++mt)
#pragma unroll
          for (int n2 = 0; n2 < 2; ++n2) {
            int q = qbase + n2 * 16 + lr;
#pragma unroll
            for (int r = 0; r < 4; ++r) {
              int key = j * 64 + mt * 16 + lq * 4 + r;
              if (key > q) s[mt][n2][r] = -INFINITY;
            }
          }
      }

      float alpha[2];
#pragma unroll
      for (int n2 = 0; n2 < 2; ++n2) {
        float mx = s[0][n2][0];
#pragma unroll
        for (int mt = 0; mt < 4; ++mt)
#pragma unroll
          for (int r = 0; r < 4; ++r) mx = fmaxf(mx, s[mt][n2][r]);
        mx = fmaxf(mx, __shfl_xor(mx, 16, 64));
        mx = fmaxf(mx, __shfl_xor(mx, 32, 64));
        float mn = fmaxf(m_s[n2], mx);
        alpha[n2] = __expf(m_s[n2] - mn);
        m_s[n2] = mn;
        float sum = 0.f;
        int q = n2 * 16 + lr;
#pragma unroll
        for (int mt = 0; mt < 4; ++mt) {
          ushort4 pk;
          float p0 = __expf(s[mt][n2][0] - mn);
          float p1 = __expf(s[mt][n2][1] - mn);
          float p2 = __expf(s[mt][n2][2] - mn);
          float p3 = __expf(s[mt][n2][3] - mn);
          sum += (p0 + p1) + (p2 + p3);
          pk.x = f2b(p0); pk.y = f2b(p1); pk.z = f2b(p2); pk.w = f2b(p3);
          *reinterpret_cast<ushort4*>(&Ps[wave][q * 72 + mt * 16 + lq * 4]) = pk;
        }
        sum += __shfl_xor(sum, 16, 64);
        sum += __shfl_xor(sum, 32, 64);
        l_s[n2] = l_s[n2] * alpha[n2] + sum;
      }

      if (lq == 0) {
        Al[wave][lr] = alpha[0];
        Al[wave][16 + lr] = alpha[1];
      }
#pragma unroll
      for (int q2 = 0; q2 < 2; ++q2) {
        f32x4 av = *reinterpret_cast<const f32x4*>(&Al[wave][q2 * 16 + lq * 4]);
#pragma unroll
        for (int r = 0; r < 4; ++r)
#pragma unroll
          for (int dt = 0; dt < 8; ++dt) o[q2][dt][r] *= av[r];
      }

#pragma unroll
      for (int kh = 0; kh < 2; ++kh) {
        bf16x8 ap[2];
#pragma unroll
        for (int q2 = 0; q2 < 2; ++q2)
          ap[q2] = *reinterpret_cast<const bf16x8*>(
              &Ps[wave][(q2 * 16 + lr) * 72 + kh * 32 + lq * 8]);
#pragma unroll
        for (int dt = 0; dt < 8; ++dt) {
          int d = dt * 16 + lr;
          int slot = (kh * 4 + lq + d) & 7;
          bf16x8 bv = *reinterpret_cast<const bf16x8*>(&Vs[d * 64 + slot * 8]);
#pragma unroll
          for (int q2 = 0; q2 < 2; ++q2)
            o[q2][dt] = __builtin_amdgcn_mfma_f32_16x16x32_bf16(ap[q2], bv, o[q2][dt], 0, 0, 0);
        }
      }
    }

    if (lq == 0) {
      Al[wave][lr] = l_s[0];
      Al[wave][16 + lr] = l_s[1];
    }
#pragma unroll
    for (int q2 = 0; q2 < 2; ++q2) {
      f32x4 lv = *reinterpret_cast<const f32x4*>(&Al[wave][q2 * 16 + lq * 4]);
#pragma unroll
      for (int r = 0; r < 4; ++r) {
        float inv = 1.0f / lv[r];
        int q = qbase + q2 * 16 + lq * 4 + r;
        u16* yp = Y + (((long long)b * T_SEQ + q) * NHEAD + h) * HDIM;
#pragma unroll
        for (int dt = 0; dt < 8; ++dt)
          yp[dt * 16 + lr] = f2b(o[q2][dt][r] * inv);
      }
    }
  }
}

extern "C" void kernel_launch(void* const* d_in, const int* in_sizes, int n_in,
                              void* d_out, int out_size, void* d_ws, size_t ws_size,
                              hipStream_t stream) {
  (void)in_sizes; (void)n_in; (void)out_size; (void)ws_size;
  const float* x  = (const float*)d_in[0];
  const float* wq = (const float*)d_in[1];
  const float* wk = (const float*)d_in[2];
  const float* wv = (const float*)d_in[3];
  const float* wo = (const float*)d_in[4];
  float* out = (float*)d_out;

  char* ws = (char*)d_ws;
  size_t off = 0;
  auto alloc = [&](size_t bytes) {
    char* p = ws + off;
    off += (bytes + 255) & ~(size_t)255;
    return p;
  };
  const size_t NTOK = (size_t)BATCH * T_SEQ;
  const size_t XE = NTOK * E_DIM;
  const size_t WE = (size_t)E_DIM * E_DIM;

  u16* xb  = (u16*)alloc(XE * 2);
  u16* wqt = (u16*)alloc(WE * 2);
  u16* wkt = (u16*)alloc(WE * 2);
  u16* wvt = (u16*)alloc(WE * 2);
  u16* wot = (u16*)alloc(WE * 2);
  u16* Qb  = (u16*)alloc(XE * 2);
  u16* Kb  = (u16*)alloc(XE * 2);
  u16* Vb  = (u16*)alloc(XE * 2);
  u16* Vt  = (u16*)alloc(XE * 2);
  u16* Yb  = (u16*)alloc(XE * 2);
  float* cost = (float*)alloc((size_t)T_SEQ * 64 * 4);
  float* sint = (float*)alloc((size_t)T_SEQ * 64 * 4);

  convert_f32_bf16<<<XE / 1024, 256, 0, stream>>>(x, xb, (int)XE);
  dim3 gw(E_DIM / 64, E_DIM / 64);
  convt_w_k<<<gw, 256, 0, stream>>>(wq, wqt);
  convt_w_k<<<gw, 256, 0, stream>>>(wk, wkt);
  convt_w_k<<<gw, 256, 0, stream>>>(wv, wvt);
  convt_w_k<<<gw, 256, 0, stream>>>(wo, wot);
  rope_tables_k<<<(T_SEQ * 64) / 256, 256, 0, stream>>>(cost, sint);

  dim3 gq(E_DIM / 256, NTOK / 256, 3);
  gemm_bt_k<<<gq, 512, 0, stream>>>(xb, wqt, wkt, wvt, Qb, Kb, Vb, nullptr,
                                    (int)NTOK, E_DIM, E_DIM);

  rope_rms_k<<<(unsigned)(NTOK * NHEAD / 4) * 2, 256, 0, stream>>>(Qb, Kb, cost, sint);

  dim3 gt(T_SEQ / 64, HDIM / 64, BATCH * NHEAD);
  transpose_v_k<<<gt, 256, 0, stream>>>(Vb, Vt);

  dim3 ga(NQT / 2, BATCH * NHEAD);
  attn_k<<<ga, 256, 0, stream>>>(Qb, Kb, Vt, Yb);

  dim3 go(E_DIM / 256, NTOK / 256, 1);
  gemm_bt_k<<<go, 512, 0, stream>>>(Yb, wot, wot, wot, nullptr, nullptr, nullptr, out,
                                    (int)NTOK, E_DIM, E_DIM);
}

// Round 2
// 655.700 us; speedup vs baseline: 1.0984x; 1.0460x over previous
//
#include <hip/hip_runtime.h>
#include <math.h>

#define T_SEQ 2048
#define BATCH 4
#define E_DIM 2048
#define NHEAD 16
#define HDIM 128
#define RMS_EPS 1.1920929e-07f
#define NQT (T_SEQ / 128)          // 16 q-tiles of 128

typedef unsigned short u16;
typedef __attribute__((ext_vector_type(8))) unsigned short u16x8;
typedef __attribute__((ext_vector_type(8))) short bf16x8;
typedef __attribute__((ext_vector_type(4))) float f32x4;

typedef const __attribute__((address_space(1))) unsigned int g_u32;
typedef __attribute__((address_space(3))) unsigned int l_u32;

static __device__ __forceinline__ u16 f2b(float f) {
  unsigned int u = __builtin_bit_cast(unsigned int, f);
  u += 0x7fffu + ((u >> 16) & 1u);
  return (u16)(u >> 16);
}
static __device__ __forceinline__ float b2f(u16 v) {
  return __builtin_bit_cast(float, ((unsigned int)v) << 16);
}

// ---------------- fp32 -> bf16 convert (x only) ----------------
__global__ __launch_bounds__(256) void convert_f32_bf16(
    const float* __restrict__ src, u16* __restrict__ dst, int n) {
  int i = (blockIdx.x * 256 + threadIdx.x) * 4;
  if (i >= n) return;
  float4 v = *reinterpret_cast<const float4*>(src + i);
  ushort4 o;
  o.x = f2b(v.x); o.y = f2b(v.y); o.z = f2b(v.z); o.w = f2b(v.w);
  *reinterpret_cast<ushort4*>(dst + i) = o;
}

// ---------------- fused fp32->bf16 convert + transpose: Wt[n][k]=W[k][n] ----
__global__ __launch_bounds__(256) void convt_w_k(
    const float* __restrict__ W, u16* __restrict__ Wt) {
  __shared__ u16 tile[64][72];
  int c0 = blockIdx.x * 64;
  int r0 = blockIdx.y * 64;
  int tid = threadIdx.x;
  int lrow = tid >> 2;
  int lcol = (tid & 3) * 16;
#pragma unroll
  for (int i = 0; i < 4; ++i) {
    float4 v = *reinterpret_cast<const float4*>(
        W + (long long)(r0 + lrow) * E_DIM + c0 + lcol + i * 4);
    tile[lrow][lcol + i * 4 + 0] = f2b(v.x);
    tile[lrow][lcol + i * 4 + 1] = f2b(v.y);
    tile[lrow][lcol + i * 4 + 2] = f2b(v.z);
    tile[lrow][lcol + i * 4 + 3] = f2b(v.w);
  }
  __syncthreads();
  int wrow = tid >> 2;
  int wcol = (tid & 3) * 16;
  u16 o[16];
#pragma unroll
  for (int i = 0; i < 16; ++i) o[i] = tile[wcol + i][wrow];
  u16* dst = Wt + (long long)(c0 + wrow) * E_DIM + r0 + wcol;
  *reinterpret_cast<u16x8*>(dst)     = *reinterpret_cast<u16x8*>(&o[0]);
  *reinterpret_cast<u16x8*>(dst + 8) = *reinterpret_cast<u16x8*>(&o[8]);
}

// ---------------- rope tables (double precision trig) ----------------
__global__ __launch_bounds__(256) void rope_tables_k(
    float* __restrict__ cost, float* __restrict__ sint) {
  int idx = blockIdx.x * 256 + threadIdx.x;
  int i = idx & 63, t = idx >> 6;
  double inv = pow(10000.0, -(double)i / 64.0);
  double ang = (double)t * inv;
  cost[idx] = (float)cos(ang);
  sint[idx] = (float)sin(ang);
}

// ---------------- fused rope + rmsnorm (in-place on bf16 Q and K) ----------
__global__ __launch_bounds__(256) void rope_rms_k(
    u16* __restrict__ Qb, u16* __restrict__ Kb, const float* __restrict__ cost,
    const float* __restrict__ sint) {
  int half = gridDim.x >> 1;
  int isK = blockIdx.x >= half;
  u16* qk = isK ? Kb : Qb;
  float outscale = isK ? 1.0f : 0.08838834764831845f;  // fold 1/sqrt(128) into Q
  int wave = threadIdx.x >> 6;
  int lane = threadIdx.x & 63;
  long long row = (long long)(blockIdx.x - (isK ? half : 0)) * 4 + wave;
  int th = (int)(row >> 4);
  int t = th & (T_SEQ - 1);
  u16* p = qk + row * HDIM;
  float x1 = b2f(p[lane]);
  float x2 = b2f(p[lane + 64]);
  float c = cost[t * 64 + lane];
  float s = sint[t * 64 + lane];
  float o1 = x1 * c - x2 * s;
  float o2 = x1 * s + x2 * c;
  float ss = o1 * o1 + o2 * o2;
#pragma unroll
  for (int m = 32; m >= 1; m >>= 1) ss += __shfl_xor(ss, m, 64);
  float r = rsqrtf(ss * (1.0f / 128.0f) + RMS_EPS) * outscale;
  p[lane] = f2b(o1 * r);
  p[lane + 64] = f2b(o2 * r);
}

// ---------------- V transpose: [B,T,H,D] -> per (b,h): [D][T] ----------------
__global__ __launch_bounds__(256) void transpose_v_k(
    const u16* __restrict__ V, u16* __restrict__ Vt) {
  __shared__ u16 tile[64][72];
  int t0 = blockIdx.x * 64, d0 = blockIdx.y * 64;
  int bh = blockIdx.z;
  int b = bh >> 4, h = bh & 15;
  int tid = threadIdx.x;
  int lrow = tid >> 3;
  int lcol = (tid & 7) * 8;
#pragma unroll
  for (int pass = 0; pass < 2; ++pass) {
    int row = lrow + pass * 32;
    const u16* src = V + ((((long long)b * T_SEQ + t0 + row) * NHEAD + h) << 7) + d0 + lcol;
    *reinterpret_cast<u16x8*>(&tile[row][lcol]) = *reinterpret_cast<const u16x8*>(src);
  }
  __syncthreads();
#pragma unroll
  for (int pass = 0; pass < 2; ++pass) {
    int drow = (tid >> 3) + pass * 32;
    int tcol = (tid & 7) * 8;
    u16x8 o;
#pragma unroll
    for (int i = 0; i < 8; ++i) o[i] = tile[tcol + i][drow];
    u16* dst = Vt + ((long long)bh * HDIM + d0 + drow) * T_SEQ + t0 + tcol;
    *reinterpret_cast<u16x8*>(dst) = o;
  }
}

// ---------------- bf16 MFMA GEMM: 256x256 tile, 8-phase schedule ------------
// C[M,N] = A[M,K] * Bt[N,K]^T.  512 threads = 8 waves (2M x 4N), each wave
// owns 128x64 output (8x4 frags of 16x16, mfma_f32_16x16x32_bf16, BK=64).
// LDS: 2 x (A 256x64 + B 256x64) bf16 = 128 KiB, double buffered.
// XCD-chunked tile remap (hw xcd = lin%8): XCD k owns 8 m-tiles x 12 (n,z)
// tiles (QKV) -> A fetched by 2 XCDs, B by 4 (was 8/8 -> 405 MB fills).
// Read schedule B-once 12/4/4/4; counted vmcnt(6); setprio around MFMA.
__global__ __launch_bounds__(512, 2) void gemm_bt_k(
    const u16* __restrict__ A,
    const u16* __restrict__ Bt0, const u16* __restrict__ Bt1, const u16* __restrict__ Bt2,
    u16* __restrict__ C0, u16* __restrict__ C1, u16* __restrict__ C2,
    float* __restrict__ Cf, int M, int N, int K) {
  // ---- XCD-aware tile remap (bijective; gx=8, gy=32, gz in {1,3}) ----
  int lin = blockIdx.x + (blockIdx.y << 3) + (blockIdx.z << 8);
  int kx = lin & 7, ii = lin >> 3;
  int by = ((kx >> 1) << 3) + (ii & 7);   // m-tile: 8-chunk per XCD-pair class
  int bx, bz;
  if (gridDim.z == 3) {
    int u = (kx & 1) * 12 + (ii >> 3);    // 24 (n,z) tiles split in two 12-slices
    bx = u & 7; bz = u >> 3;
  } else {
    bx = ((kx & 1) << 2) + (ii >> 3);     // 8 n-tiles split in two 4-slices
    bz = 0;
  }
  const u16* Bt = bz == 0 ? Bt0 : (bz == 1 ? Bt1 : Bt2);
  u16* C = bz == 0 ? C0 : (bz == 1 ? C1 : C2);

  __shared__ u16 As[2][256 * 64];
  __shared__ u16 Bs[2][256 * 64];
  const int tid = threadIdx.x;
  const int lane = tid & 63, wave = tid >> 6;
  const int wm = wave >> 2, wn = wave & 3;   // 2 x 4 wave grid
  const int m0 = by * 256, n0 = bx * 256;
  const int lr = lane & 15, lq = lane >> 4, l7 = lane & 7;
  const int NT = K >> 6;

  // Staging halves: A half h = rows with bit6==h (h0 = mt0-3, read p1/p2);
  // B half h = rows with bit5==h (h0 = nt0-1; ALL B read in p1).
  int rowA[2][2], rowB[2][2];
  const u16* gA[2][2];
  const u16* gB[2][2];
#pragma unroll
  for (int l = 0; l < 2; ++l) {
    int rihb = l * 64 + wave * 8;
#pragma unroll
    for (int h = 0; h < 2; ++h) {
      int ra = ((rihb >> 6) << 7) + h * 64 + (rihb & 63);
      int rb = ((rihb >> 5) << 6) + h * 32 + (rihb & 31);
      rowA[h][l] = ra;
      rowB[h][l] = rb;
      int rA = ra + (lane >> 3);
      int rB = rb + (lane >> 3);
      // inverse-swizzled global source: LDS[r][c] <- G[r][c ^ (r&7)]
      gA[h][l] = A + (long long)(m0 + rA) * K + ((l7 ^ (rA & 7)) * 8);
      gB[h][l] = Bt + (long long)(n0 + rB) * K + ((l7 ^ (rB & 7)) * 8);
    }
  }

  f32x4 acc[8][4] = {};

#define GLDS(gp, lp) \
  __builtin_amdgcn_global_load_lds((g_u32*)(gp), (l_u32*)(lp), 16, 0, 0)
#define LD_A(mt, ks)                                                          \
  (*reinterpret_cast<const bf16x8*>(                                          \
      Ab + (wm * 128 + (mt) * 16 + lr) * 64 + ((((ks) << 2) + lq) ^ l7) * 8))
#define LD_B(nt, ks)                                                          \
  (*reinterpret_cast<const bf16x8*>(                                          \
      Bb + (wn * 64 + (nt) * 16 + lr) * 64 + ((((ks) << 2) + lq) ^ l7) * 8))
#define MFMA_PH(ph)                                                           \
  _Pragma("unroll") for (int mi = 0; mi < 2; ++mi)                            \
  _Pragma("unroll") for (int ni = 0; ni < 4; ++ni)                            \
  _Pragma("unroll") for (int ks = 0; ks < 2; ++ks)                            \
    acc[(ph) * 2 + mi][ni] = __builtin_amdgcn_mfma_f32_16x16x32_bf16(         \
        aA[mi][ks], bB[ni][ks], acc[(ph) * 2 + mi][ni], 0, 0, 0);

  // prologue: tile0 fully (8 loads) + tile1 {B0,B1,A0} (6 loads);
  // vmcnt(6) completes tile0, keeps 3 halves in flight.
  GLDS(gB[0][0], &Bs[0][rowB[0][0] * 64]); GLDS(gB[0][1], &Bs[0][rowB[0][1] * 64]);
  GLDS(gB[1][0], &Bs[0][rowB[1][0] * 64]); GLDS(gB[1][1], &Bs[0][rowB[1][1] * 64]);
  GLDS(gA[0][0], &As[0][rowA[0][0] * 64]); GLDS(gA[0][1], &As[0][rowA[0][1] * 64]);
  GLDS(gA[1][0], &As[0][rowA[1][0] * 64]); GLDS(gA[1][1], &As[0][rowA[1][1] * 64]);
  GLDS(gB[0][0] + 64, &Bs[1][rowB[0][0] * 64]); GLDS(gB[0][1] + 64, &Bs[1][rowB[0][1] * 64]);
  GLDS(gB[1][0] + 64, &Bs[1][rowB[1][0] * 64]); GLDS(gB[1][1] + 64, &Bs[1][rowB[1][1] * 64]);
  GLDS(gA[0][0] + 64, &As[1][rowA[0][0] * 64]); GLDS(gA[0][1] + 64, &As[1][rowA[0][1] * 64]);
  asm volatile("s_waitcnt vmcnt(6)" ::: "memory");
  __builtin_amdgcn_s_barrier();
  __builtin_amdgcn_sched_barrier(0);

  for (int t = 0; t < NT; ++t) {
    const u16* Ab = As[t & 1];
    const u16* Bb = Bs[t & 1];
    u16* An = (u16*)As[(t & 1) ^ 1];
    u16* Ac = (u16*)As[t & 1];
    u16* Bc = (u16*)Bs[t & 1];
    const bool g1 = (t + 1 < NT), g2 = (t + 2 < NT);
    bf16x8 aA[2][2], bB[4][2];

    // ---- phase 1: reads aA(mt0,1)+bB(all) = 12; stage A(t+1,h1)->other buf
#pragma unroll
    for (int mi = 0; mi < 2; ++mi) { aA[mi][0] = LD_A(mi, 0); aA[mi][1] = LD_A(mi, 1); }
#pragma unroll
    for (int ni = 0; ni < 4; ++ni) { bB[ni][0] = LD_B(ni, 0); bB[ni][1] = LD_B(ni, 1); }
    if (g1) {
      GLDS(gA[1][0] + 64, &An[rowA[1][0] * 64]);
      GLDS(gA[1][1] + 64, &An[rowA[1][1] * 64]);
    }
    asm volatile("s_waitcnt lgkmcnt(8)" ::: "memory");   // pre-drain (12 reads)
    __builtin_amdgcn_s_barrier();
    asm volatile("s_waitcnt lgkmcnt(0)" ::: "memory");
    __builtin_amdgcn_sched_barrier(0);
    __builtin_amdgcn_s_setprio(1);
    MFMA_PH(0);
    __builtin_amdgcn_s_setprio(0);
    __builtin_amdgcn_s_barrier();

    // ---- phase 2: reads aA(mt2,3) = 4; stage B(t+2,h0) (B all read in p1)
#pragma unroll
    for (int mi = 0; mi < 2; ++mi) { aA[mi][0] = LD_A(2 + mi, 0); aA[mi][1] = LD_A(2 + mi, 1); }
    if (g2) {
      GLDS(gB[0][0] + 128, &Bc[rowB[0][0] * 64]);
      GLDS(gB[0][1] + 128, &Bc[rowB[0][1] * 64]);
    }
    __builtin_amdgcn_s_barrier();
    asm volatile("s_waitcnt lgkmcnt(0)" ::: "memory");
    __builtin_amdgcn_sched_barrier(0);
    __builtin_amdgcn_s_setprio(1);
    MFMA_PH(1);
    __builtin_amdgcn_s_setprio(0);
    __builtin_amdgcn_s_barrier();

    // ---- phase 3: reads aA(mt4,5) = 4; stage B(t+2,h1)
#pragma unroll
    for (int mi = 0; mi < 2; ++mi) { aA[mi][0] = LD_A(4 + mi, 0); aA[mi][1] = LD_A(4 + mi, 1); }
    if (g2) {
      GLDS(gB[1][0] + 128, &Bc[rowB[1][0] * 64]);
      GLDS(gB[1][1] + 128, &Bc[rowB[1][1] * 64]);
    }
    __builtin_amdgcn_s_barrier();
    asm volatile("s_waitcnt lgkmcnt(0)" ::: "memory");
    __builtin_amdgcn_sched_barrier(0);
    __builtin_amdgcn_s_setprio(1);
    MFMA_PH(2);
    __builtin_amdgcn_s_setprio(0);
    __builtin_amdgcn_s_barrier();

    // ---- phase 4: reads aA(mt6,7) = 4; stage A(t+2,h0); counted vmcnt
#pragma unroll
    for (int mi = 0; mi < 2; ++mi) { aA[mi][0] = LD_A(6 + mi, 0); aA[mi][1] = LD_A(6 + mi, 1); }
    if (g2) {
      GLDS(gA[0][0] + 128, &Ac[rowA[0][0] * 64]);
      GLDS(gA[0][1] + 128, &Ac[rowA[0][1] * 64]);
    }
    __builtin_amdgcn_s_barrier();
    asm volatile("s_waitcnt lgkmcnt(0)" ::: "memory");
    __builtin_amdgcn_sched_barrier(0);
    __builtin_amdgcn_s_setprio(1);
    MFMA_PH(3);
    __builtin_amdgcn_s_setprio(0);
    if (t < NT - 2) {
      asm volatile("s_waitcnt vmcnt(6)" ::: "memory");   // 3 halves stay in flight
    } else {
      asm volatile("s_waitcnt vmcnt(0)" ::: "memory");   // tail drain
    }
    __builtin_amdgcn_s_barrier();
    __builtin_amdgcn_sched_barrier(0);

    // advance K pointers (constant +64/+128 elem offsets fold into loads)
#pragma unroll
    for (int l = 0; l < 2; ++l)
#pragma unroll
      for (int h = 0; h < 2; ++h) { gA[h][l] += 64; gB[h][l] += 64; }
  }
#undef LD_A
#undef LD_B
#undef MFMA_PH
#undef GLDS

  // epilogue: C col = lane&15, row = (lane>>4)*4 + reg   (16x16 C/D layout)
#pragma unroll
  for (int mt = 0; mt < 8; ++mt)
#pragma unroll
    for (int nt = 0; nt < 4; ++nt) {
      long long col = n0 + wn * 64 + nt * 16 + lr;
#pragma unroll
      for (int r = 0; r < 4; ++r) {
        long long row = m0 + wm * 128 + mt * 16 + lq * 4 + r;
        float v = acc[mt][nt][r];
        if (Cf) Cf[row * N + col] = v;
        else C[row * N + col] = f2b(v);
      }
    }
}

// ---------------- causal flash attention v3 (XCD-remapped grid) ----------
__global__ __launch_bounds__(256, 3) void attn_k(
    const u16* __restrict__ Q, const u16* __restrict__ K,
    const u16* __restrict__ Vt, u16* __restrict__ Y) {
  __shared__ u16 Ks[64 * 128];        // row=key, 16 chunks/row, slot=(g+key)&15
  __shared__ u16 Vs[128 * 64];        // row=d, 8 chunks/row, slot=(g+d)&7
  __shared__ u16 Ps[4][32 * 72];      // per-wave P [q][key], pad 64->72
  __shared__ float Al[4][32];         // per-wave alpha / l broadcast
  // XCD remap (hw xcd = lin%8; gx = NQT/2 = 8): XCD k owns bh in [8k, 8k+8)
  // for all pairs -> each XCD streams 8 KV heads (8 MB) instead of all 64.
  int lin = blockIdx.x + (blockIdx.y << 3);
  int pair = (lin >> 6);              // 0..NQT/2-1
  int bh = ((lin & 7) << 3) + ((lin >> 3) & 7);
  int b = bh >> 4, h = bh & 15;
  int tid = threadIdx.x, lane = tid & 63, wave = tid >> 6;
  int lr = lane & 15, lq = lane >> 4;

  const u16* kp[4];
  const u16* vp[4];
#pragma unroll
  for (int p = 0; p < 4; ++p) {
    int c = p * 256 + wave * 64 + lane;
    int key = c >> 4, sk = c & 15, gk = (sk - key) & 15;
    kp[p] = K + (((long long)b * T_SEQ + key) * NHEAD + h) * HDIM + gk * 8;
    int d = c >> 3, sv = c & 7, gv = (sv - d) & 7;
    vp[p] = Vt + ((long long)bh * HDIM + d) * T_SEQ + gv * 8;
  }

#pragma unroll 1
  for (int phase = 0; phase < 2; ++phase) {
    int qt = phase == 0 ? (NQT - 1 - pair) : pair;
    int qbase = qt * 128 + wave * 32;

    bf16x8 aq[2][4];
#pragma unroll
    for (int n2 = 0; n2 < 2; ++n2) {
      const u16* qp = Q + (((long long)b * T_SEQ + qbase + n2 * 16 + lr) * NHEAD + h) * HDIM;
#pragma unroll
      for (int kt = 0; kt < 4; ++kt)
        aq[n2][kt] = *reinterpret_cast<const bf16x8*>(qp + kt * 32 + lq * 8);
    }

    float m_s[2], l_s[2];
#pragma unroll
    for (int n2 = 0; n2 < 2; ++n2) { m_s[n2] = -INFINITY; l_s[n2] = 0.f; }
    f32x4 o[2][8] = {};

    int niter = 2 * qt + 2;
    for (int j = 0; j < niter; ++j) {
      __syncthreads();
#pragma unroll
      for (int p = 0; p < 4; ++p) {
        __builtin_amdgcn_global_load_lds(
            (g_u32*)(kp[p] + (long long)j * 64 * NHEAD * HDIM),
            (l_u32*)(Ks + p * 2048 + wave * 512), 16, 0, 0);
        __builtin_amdgcn_global_load_lds(
            (g_u32*)(vp[p] + j * 64),
            (l_u32*)(Vs + p * 2048 + wave * 512), 16, 0, 0);
      }
      __syncthreads();

      f32x4 s[4][2];
#pragma unroll
      for (int mt = 0; mt < 4; ++mt) {
        int key = mt * 16 + lr;
        bf16x8 ak[4];
#pragma unroll
        for (int kt = 0; kt < 4; ++kt) {
          int slot = (kt * 4 + lq + key) & 15;
          ak[kt] = *reinterpret_cast<const bf16x8*>(&Ks[key * 128 + slot * 8]);
        }
#pragma unroll
        for (int n2 = 0; n2 < 2; ++n2) {
          f32x4 acc = {};
#pragma unroll
          for (int kt = 0; kt < 4; ++kt)
            acc = __builtin_amdgcn_mfma_f32_16x16x32_bf16(ak[kt], aq[n2][kt], acc, 0, 0, 0);
          s[mt][n2] = acc;
        }
      }

      if (j >= 2 * qt) {
#pragma unroll
        for (int mt = 0; mt < 4; ++mt)
#pragma unroll
          for (int n2 = 0; n2 < 2; ++n2) {
            int q = qbase + n2 * 16 + lr;
#pragma unroll
            for (int r = 0; r < 4; ++r) {
              int key = j * 64 + mt * 16 + lq * 4 + r;
              if (key > q) s[mt][n2][r] = -INFINITY;
            }
          }
      }

      float alpha[2];
#pragma unroll
      for (int n2 = 0; n2 < 2; ++n2) {
        float mx = s[0][n2][0];
#pragma unroll
        for (int mt = 0; mt < 4; ++mt)
#pragma unroll
          for (int r = 0; r < 4; ++r) mx = fmaxf(mx, s[mt][n2][r]);
        mx = fmaxf(mx, __shfl_xor(mx, 16, 64));
        mx = fmaxf(mx, __shfl_xor(mx, 32, 64));
        float mn = fmaxf(m_s[n2], mx);
        alpha[n2] = __expf(m_s[n2] - mn);
        m_s[n2] = mn;
        float sum = 0.f;
        int q = n2 * 16 + lr;
#pragma unroll
        for (int mt = 0; mt < 4; ++mt) {
          ushort4 pk;
          float p0 = __expf(s[mt][n2][0] - mn);
          float p1 = __expf(s[mt][n2][1] - mn);
          float p2 = __expf(s[mt][n2][2] - mn);
          float p3 = __expf(s[mt][n2][3] - mn);
          sum += (p0 + p1) + (p2 + p3);
          pk.x = f2b(p0); pk.y = f2b(p1); pk.z = f2b(p2); pk.w = f2b(p3);
          *reinterpret_cast<ushort4*>(&Ps[wave][q * 72 + mt * 16 + lq * 4]) = pk;
        }
        sum += __shfl_xor(sum, 16, 64);
        sum += __shfl_xor(sum, 32, 64);
        l_s[n2] = l_s[n2] * alpha[n2] + sum;
      }

      if (lq == 0) {
        Al[wave][lr] = alpha[0];
        Al[wave][16 + lr] = alpha[1];
      }
#pragma unroll
      for (int q2 = 0; q2 < 2; ++q2) {
        f32x4 av = *reinterpret_cast<const f32x4*>(&Al[wave][q2 * 16 + lq * 4]);
#pragma unroll
        for (int r = 0; r < 4; ++r)
#pragma unroll
          for (int dt = 0; dt < 8; ++dt) o[q2][dt][r] *= av[r];
      }

#pragma unroll
      for (int kh = 0; kh < 2; ++kh) {
        bf16x8 ap[2];
#pragma unroll
        for (int q2 = 0; q2 < 2; ++q2)
          ap[q2] = *reinterpret_cast<const bf16x8*>(
              &Ps[wave][(q2 * 16 + lr) * 72 + kh * 32 + lq * 8]);
#pragma unroll
        for (int dt = 0; dt < 8; ++dt) {
          int d = dt * 16 + lr;
          int slot = (kh * 4 + lq + d) & 7;
          bf16x8 bv = *reinterpret_cast<const bf16x8*>(&Vs[d * 64 + slot * 8]);
#pragma unroll
          for (int q2 = 0; q2 < 2; ++q2)
            o[q2][dt] = __builtin_amdgcn_mfma_f32_16x16x32_bf16(ap[q2], bv, o[q2][dt], 0, 0, 0);
        }
      }
    }

    if (lq == 0) {
      Al[wave][lr] = l_s[0];
      Al[wave][16 + lr] = l_s[1];
    }
#pragma unroll
    for (int q2 = 0; q2 < 2; ++q2) {
      f32x4 lv = *reinterpret_cast<const f32x4*>(&Al[wave][q2 * 16 + lq * 4]);
#pragma unroll
      for (int r = 0; r < 4; ++r) {
        float inv = 1.0f / lv[r];
        int q = qbase + q2 * 16 + lq * 4 + r;
        u16* yp = Y + (((long long)b * T_SEQ + q) * NHEAD + h) * HDIM;
#pragma unroll
        for (int dt = 0; dt < 8; ++dt)
          yp[dt * 16 + lr] = f2b(o[q2][dt][r] * inv);
      }
    }
  }
}

extern "C" void kernel_launch(void* const* d_in, const int* in_sizes, int n_in,
                              void* d_out, int out_size, void* d_ws, size_t ws_size,
                              hipStream_t stream) {
  (void)in_sizes; (void)n_in; (void)out_size; (void)ws_size;
  const float* x  = (const float*)d_in[0];
  const float* wq = (const float*)d_in[1];
  const float* wk = (const float*)d_in[2];
  const float* wv = (const float*)d_in[3];
  const float* wo = (const float*)d_in[4];
  float* out = (float*)d_out;

  char* ws = (char*)d_ws;
  size_t off = 0;
  auto alloc = [&](size_t bytes) {
    char* p = ws + off;
    off += (bytes + 255) & ~(size_t)255;
    return p;
  };
  const size_t NTOK = (size_t)BATCH * T_SEQ;
  const size_t XE = NTOK * E_DIM;
  const size_t WE = (size_t)E_DIM * E_DIM;

  u16* xb  = (u16*)alloc(XE * 2);
  u16* wqt = (u16*)alloc(WE * 2);
  u16* wkt = (u16*)alloc(WE * 2);
  u16* wvt = (u16*)alloc(WE * 2);
  u16* wot = (u16*)alloc(WE * 2);
  u16* Qb  = (u16*)alloc(XE * 2);
  u16* Kb  = (u16*)alloc(XE * 2);
  u16* Vb  = (u16*)alloc(XE * 2);
  u16* Vt  = (u16*)alloc(XE * 2);
  u16* Yb  = (u16*)alloc(XE * 2);
  float* cost = (float*)alloc((size_t)T_SEQ * 64 * 4);
  float* sint = (float*)alloc((size_t)T_SEQ * 64 * 4);

  convert_f32_bf16<<<XE / 1024, 256, 0, stream>>>(x, xb, (int)XE);
  dim3 gw(E_DIM / 64, E_DIM / 64);
  convt_w_k<<<gw, 256, 0, stream>>>(wq, wqt);
  convt_w_k<<<gw, 256, 0, stream>>>(wk, wkt);
  convt_w_k<<<gw, 256, 0, stream>>>(wv, wvt);
  convt_w_k<<<gw, 256, 0, stream>>>(wo, wot);
  rope_tables_k<<<(T_SEQ * 64) / 256, 256, 0, stream>>>(cost, sint);

  dim3 gq(E_DIM / 256, NTOK / 256, 3);
  gemm_bt_k<<<gq, 512, 0, stream>>>(xb, wqt, wkt, wvt, Qb, Kb, Vb, nullptr,
                                    (int)NTOK, E_DIM, E_DIM);

  rope_rms_k<<<(unsigned)(NTOK * NHEAD / 4) * 2, 256, 0, stream>>>(Qb, Kb, cost, sint);

  dim3 gt(T_SEQ / 64, HDIM / 64, BATCH * NHEAD);
  transpose_v_k<<<gt, 256, 0, stream>>>(Vb, Vt);

  dim3 ga(NQT / 2, BATCH * NHEAD);
  attn_k<<<ga, 256, 0, stream>>>(Qb, Kb, Vt, Yb);

  dim3 go(E_DIM / 256, NTOK / 256, 1);
  gemm_bt_k<<<go, 512, 0, stream>>>(Yb, wot, wot, wot, nullptr, nullptr, nullptr, out,
                                    (int)NTOK, E_DIM, E_DIM);
}